// Round 7
// baseline (7604.778 us; speedup 1.0000x reference)
//
#include <hip/hip_runtime.h>
#include <math.h>

// MixedOp (SPDNet DARTS): per (b,c): s_k = W_k X W_k^T, G0 = sum w_k s_k,
// Sq/Si = G0^{+-1/2} (eigh), T_k = Si s_k Si, L_k = logm(T_k) (eigh),
// U = sum w_k L_k, out = Sq expm(U) Sq (eigh).
//
// PRIMARY (wave-synchronous, needs 50.33 MB d_ws): each 32x32 eigh runs on
// ONE 64-lane wave (16 rotation pairs x 4 lanes) using per-wave in-order LDS
// + compiler fences instead of __syncthreads (~5000 barriers/block -> ~25).
// 4 T_k eighs run concurrently on the block's 4 waves. s_k (f32) and Sq
// (f64) spill to d_ws so LDS stays at 75.3 KB -> 2 blocks/CU.
//
// FALLBACK (if ws_size too small): Round-3 validated block-synchronous
// kernel (no workspace, 6654 us, absmax 0.0). Deterministic branch on
// ws_size (constant per problem) -> graph-capture safe.

#define NTH 256
#define LDA 33  // padded row stride (doubles) for 32x32 LDS matrices

// Wave-internal ordering fence: per-wave LDS ops are in-order on CDNA; this
// stops the compiler from reordering across the phase boundary and drains
// outstanding DS ops. NOT a block barrier.
#define WV_SYNC()                                         \
  do {                                                    \
    asm volatile("s_waitcnt lgkmcnt(0)" ::: "memory");    \
    __builtin_amdgcn_sched_barrier(0);                    \
  } while (0)

// ======================= PRIMARY (wave-synchronous) =======================

struct SM {
  double W4[4][32 * LDA];  // work mats: phase1 staging overlay / T_k / L'_k
  double V4[4][32 * LDA];  // eigenvector mats / temps
  double Si[32 * LDA];     // G0^{-1/2}
  double ew4[4][32];       // eigenvalues per wave-slot
};
// Phase-1 staging overlay on W4/V4 (byte offsets from &W4[0][0]):
//   Xs  f32 [64][65]  @ 0      (16640 B)
//   Ys  f64 [32][65]  @ 16640  (16640 B)
//   Wst f32 [32][65]  @ 33280  ( 8320 B)
//   G0  f64 [1056]    @ 41600  ( 8448 B)   (all < 67584 = W4+V4)

// ---- wave-local matmul D = A*B (32x32, LDS, stride LDA), 64 lanes ----
__device__ inline void mm_nn_wave(double* __restrict__ D, const double* __restrict__ A,
                                  const double* __restrict__ B, int lane) {
  const int j = lane & 31, hi = lane >> 5;
  double cb[32];
#pragma unroll
  for (int m = 0; m < 32; ++m) cb[m] = B[m * LDA + j];
#pragma unroll 4
  for (int t = 0; t < 16; ++t) {
    const int i = 2 * t + hi;
    double acc = 0.0;
#pragma unroll
    for (int m = 0; m < 32; ++m) acc = fma(A[i * LDA + m], cb[m], acc);
    D[i * LDA + j] = acc;
  }
}

// ---- block-wide matmul D = A*B (32x32), 256 threads ----
__device__ inline void mm_nn_blk(double* __restrict__ D, const double* __restrict__ A,
                                 const double* __restrict__ B, int tid) {
  const int j = tid & 31;
  double cb[32];
#pragma unroll
  for (int m = 0; m < 32; ++m) cb[m] = B[m * LDA + j];
#pragma unroll
  for (int t = 0; t < 4; ++t) {
    const int i = 8 * t + (tid >> 5);
    double acc = 0.0;
#pragma unroll
    for (int m = 0; m < 32; ++m) acc = fma(A[i * LDA + m], cb[m], acc);
    D[i * LDA + j] = acc;
  }
}

// ---- wave-local cyclic Jacobi eigh of symmetric 32x32 A (destroyed) ----
// V <- eigenvectors (columns), ewv <- eigenvalues. 64 lanes: 16 pairs x 4.
// No __syncthreads inside: per-wave lockstep + WV_SYNC fences only.
__device__ void eigh_wave(double* __restrict__ A, double* __restrict__ V,
                          double* __restrict__ ewv, int lane) {
  double fro2 = 0.0;
  for (int t = 0; t < 16; ++t) {
    const int e = t * 64 + lane, i = e >> 5, j = e & 31;
    const double v = A[i * LDA + j];
    fro2 += v * v;
    V[i * LDA + j] = (i == j) ? 1.0 : 0.0;
  }
#pragma unroll
  for (int m = 1; m < 64; m <<= 1) fro2 += __shfl_xor(fro2, m, 64);
  const double tol2 = 1e-20 * fro2;          // off_F <= 1e-10 * ||A||_F
  const double thr = tol2 * (1.0 / 4096.0);  // per-rotation skip threshold

  const int pi = lane >> 2, g = lane & 3;
  for (int sweep = 0; sweep < 14; ++sweep) {
    WV_SYNC();
    double off2 = 0.0;
    for (int t = 0; t < 16; ++t) {
      const int e = t * 64 + lane, i = e >> 5, j = e & 31;
      const double v = A[i * LDA + j];
      if (i != j) off2 += v * v;
    }
#pragma unroll
    for (int m = 1; m < 64; m <<= 1) off2 += __shfl_xor(off2, m, 64);
    if (off2 <= tol2) break;  // wave-uniform

    for (int r = 0; r < 31; ++r) {
      int p, q;
      if (pi == 0) { p = 31; q = r; }
      else { p = (r + pi) % 31; q = (r - pi + 31) % 31; }
      if (p > q) { const int t_ = p; p = q; q = t_; }
      WV_SYNC();  // prev round's col writes visible
      const double apq = A[p * LDA + q];
      const double app = A[p * LDA + p], aqq = A[q * LDA + q];
      const bool active = (apq * apq > thr);
      double c = 1.0, s = 0.0;
      if (active) {
        const double tau = (aqq - app) / (2.0 * apq);
        const double tt = ((tau >= 0.0) ? 1.0 : -1.0) / (fabs(tau) + sqrt(1.0 + tau * tau));
        c = 1.0 / sqrt(1.0 + tt * tt);
        s = tt * c;
        // row phase: A <- J^T A  (rows p,q; this lane's cols j = g+4t)
        for (int t = 0; t < 8; ++t) {
          const int j = g + 4 * t;
          const double ap = A[p * LDA + j], aq = A[q * LDA + j];
          A[p * LDA + j] = c * ap - s * aq;
          A[q * LDA + j] = s * ap + c * aq;
        }
      }
      WV_SYNC();  // row phase complete before col phase
      if (active) {
        // col phase: A <- A J ; V <- V J  (cols p,q; rows i = g+4t)
        for (int t = 0; t < 8; ++t) {
          const int i2 = g + 4 * t;
          double ap = A[i2 * LDA + p], aq = A[i2 * LDA + q];
          A[i2 * LDA + p] = c * ap - s * aq;
          A[i2 * LDA + q] = s * ap + c * aq;
          ap = V[i2 * LDA + p]; aq = V[i2 * LDA + q];
          V[i2 * LDA + p] = c * ap - s * aq;
          V[i2 * LDA + q] = s * ap + c * aq;
        }
      }
    }
  }
  WV_SYNC();
  if (lane < 32) ewv[lane] = A[lane * LDA + lane];
  WV_SYNC();
}

__global__ __launch_bounds__(NTH, 2) void mixedop_kernel(
    const float* __restrict__ xg, const float* __restrict__ wg,
    const float* __restrict__ Wg, float* __restrict__ outg,
    float* __restrict__ ws_s, double* __restrict__ ws_sq) {
  __shared__ SM sm;
  const int bc = blockIdx.x;
  const int tid = threadIdx.x;
  const int lane = tid & 63;
  const int wv = tid >> 6;

  // staging overlay pointers
  char* base = (char*)&sm.W4[0][0];
  float* Xs = (float*)base;                    // [64][65]
  double* Ys = (double*)(base + 16640);        // [32][65]
  float* Wst = (float*)(base + 33280);         // [32][65]
  double* G0 = (double*)(base + 41600);        // [1056]

  // ---- Phase 1: X load, G0 zero ----
  for (int idx = tid; idx < 1056; idx += NTH) G0[idx] = 0.0;
  const float* xsrc = xg + (size_t)bc * 4096;
  for (int idx = tid; idx < 4096; idx += NTH)
    Xs[(idx >> 6) * 65 + (idx & 63)] = xsrc[idx];
  __syncthreads();

  for (int k = 0; k < 4; ++k) {
    const float* wsrc = Wg + k * 2048;
    for (int idx = tid; idx < 2048; idx += NTH)
      Wst[(idx >> 6) * 65 + (idx & 63)] = wsrc[idx];
    __syncthreads();
    // Y = W_k * X  [32 x 64], X-column cached in regs
    {
      const int j = tid & 63;
      float cx[64];
#pragma unroll
      for (int m = 0; m < 64; ++m) cx[m] = Xs[m * 65 + j];
#pragma unroll
      for (int t = 0; t < 8; ++t) {
        const int o = 4 * t + (tid >> 6);
        double acc = 0.0;
#pragma unroll
        for (int m = 0; m < 64; ++m)
          acc = fma((double)Wst[o * 65 + m], (double)cx[m], acc);
        Ys[o * 65 + j] = acc;
      }
    }
    __syncthreads();
    // s_k = Y * W_k^T -> ws (f32) ; G0 += w_k s_k  (f64)
    {
      const double wkk = (double)wg[k];
      const int p = tid & 31;
      float cw[64];
#pragma unroll
      for (int m = 0; m < 64; ++m) cw[m] = Wst[p * 65 + m];
#pragma unroll
      for (int t = 0; t < 4; ++t) {
        const int o = 8 * t + (tid >> 5);
        double acc = 0.0;
#pragma unroll
        for (int m = 0; m < 64; ++m)
          acc = fma(Ys[o * 65 + m], (double)cw[m], acc);
        const int e = o * 32 + p;  // == 256*t + tid (coalesced)
        ws_s[(size_t)bc * 4096 + k * 1024 + e] = (float)acc;
        G0[o * LDA + p] += wkk * acc;
      }
    }
    __syncthreads();
  }

  // ---- Phase 3: eigh(G0) -> Sq (to ws), Si (LDS) ----
  for (int idx = tid; idx < 1024; idx += NTH) {
    const int i = idx >> 5, j = idx & 31;
    sm.W4[0][i * LDA + j] = G0[i * LDA + j];
  }
  __syncthreads();
  if (wv == 0) eigh_wave(sm.W4[0], sm.V4[0], sm.ew4[0], lane);
  __syncthreads();
  {  // P = V D^{1/2} -> W4[1] ; P2 = V D^{-1/2} -> W4[2]
    const int j = tid & 31;
    const double lam = sm.ew4[0][j];
    const double sq = sqrt(fmax(lam, 0.0));
    const double isq = 1.0 / sqrt(fmax(lam, 1e-12));
#pragma unroll
    for (int t = 0; t < 4; ++t) {
      const int i = 8 * t + (tid >> 5);
      const double v = sm.V4[0][i * LDA + j];
      sm.W4[1][i * LDA + j] = v * sq;
      sm.W4[2][i * LDA + j] = v * isq;
    }
  }
  __syncthreads();
  {  // Sq = P V^T -> ws_sq ; Si = P2 V^T -> sm.Si   (B^T: cache V row j)
    const int j = tid & 31;
    double cb[32];
#pragma unroll
    for (int m = 0; m < 32; ++m) cb[m] = sm.V4[0][j * LDA + m];
#pragma unroll
    for (int t = 0; t < 4; ++t) {
      const int i = 8 * t + (tid >> 5);
      double a1 = 0.0, a2 = 0.0;
#pragma unroll
      for (int m = 0; m < 32; ++m) {
        a1 = fma(sm.W4[1][i * LDA + m], cb[m], a1);
        a2 = fma(sm.W4[2][i * LDA + m], cb[m], a2);
      }
      ws_sq[(size_t)bc * 1024 + i * 32 + j] = a1;  // coalesced
      sm.Si[i * LDA + j] = a2;
    }
  }
  __syncthreads();

  // ---- Phase 4/5: per wave k: T_k = Si s_k Si ; eigh ; L'_k = w_k V log V^T ----
  {
    const int k = wv;
    double* Ak = sm.W4[k];
    double* Vk = sm.V4[k];
    // stage s_k from ws (f32 -> f64)
    for (int t = 0; t < 16; ++t) {
      const int e = t * 64 + lane;
      Ak[(e >> 5) * LDA + (e & 31)] =
          (double)ws_s[(size_t)bc * 4096 + k * 1024 + e];
    }
    WV_SYNC();
    mm_nn_wave(Vk, sm.Si, Ak, lane);  // R = Si * s_k
    WV_SYNC();
    mm_nn_wave(Ak, Vk, sm.Si, lane);  // T = R * Si
    WV_SYNC();
    eigh_wave(Ak, Vk, sm.ew4[k], lane);
    {  // P = V diag(log lam) -> Ak (eigh-dead)
      const int j = lane & 31, hi = lane >> 5;
      const double lgl = log(fmax(sm.ew4[k][j], 1e-12));
#pragma unroll
      for (int t = 0; t < 16; ++t) {
        const int i = 2 * t + hi;
        Ak[i * LDA + j] = Vk[i * LDA + j] * lgl;
      }
    }
    WV_SYNC();
    {  // L'_k = w_k * P * V^T -> regs -> overwrite Ak (reads all precede writes)
      const double wkk = (double)wg[k];
      const int j = lane & 31, hi = lane >> 5;
      double cb[32];
#pragma unroll
      for (int m = 0; m < 32; ++m) cb[m] = Vk[j * LDA + m];
      double accv[16];
#pragma unroll
      for (int t = 0; t < 16; ++t) {
        const int i = 2 * t + hi;
        double a = 0.0;
#pragma unroll
        for (int m = 0; m < 32; ++m) a = fma(Ak[i * LDA + m], cb[m], a);
        accv[t] = wkk * a;
      }
      WV_SYNC();
#pragma unroll
      for (int t = 0; t < 16; ++t) Ak[(2 * t + hi) * LDA + j] = accv[t];
    }
  }
  __syncthreads();

  // ---- Phase 6: U = sum L'_k ; eigh(U) ; E = expm(U) ----
  for (int idx = tid; idx < 1024; idx += NTH) {
    const int i = idx >> 5, j = idx & 31;
    sm.V4[1][i * LDA + j] = sm.W4[0][i * LDA + j] + sm.W4[1][i * LDA + j] +
                            sm.W4[2][i * LDA + j] + sm.W4[3][i * LDA + j];
  }
  __syncthreads();
  if (wv == 0) eigh_wave(sm.V4[1], sm.V4[0], sm.ew4[0], lane);
  __syncthreads();
  {  // Pe = V diag(exp) -> V4[2]
    const int j = tid & 31;
    const double ex = exp(sm.ew4[0][j]);
#pragma unroll
    for (int t = 0; t < 4; ++t) {
      const int i = 8 * t + (tid >> 5);
      sm.V4[2][i * LDA + j] = sm.V4[0][i * LDA + j] * ex;
    }
  }
  __syncthreads();
  {  // E = Pe V^T -> V4[3]
    const int j = tid & 31;
    double cb[32];
#pragma unroll
    for (int m = 0; m < 32; ++m) cb[m] = sm.V4[0][j * LDA + m];
#pragma unroll
    for (int t = 0; t < 4; ++t) {
      const int i = 8 * t + (tid >> 5);
      double acc = 0.0;
#pragma unroll
      for (int m = 0; m < 32; ++m) acc = fma(sm.V4[2][i * LDA + m], cb[m], acc);
      sm.V4[3][i * LDA + j] = acc;
    }
  }
  __syncthreads();
  // reload Sq
  for (int idx = tid; idx < 1024; idx += NTH)
    sm.W4[0][(idx >> 5) * LDA + (idx & 31)] = ws_sq[(size_t)bc * 1024 + idx];
  __syncthreads();
  mm_nn_blk(sm.W4[1], sm.W4[0], sm.V4[3], tid);  // F1 = Sq * E
  __syncthreads();
  {  // out = F1 * Sq -> global f32
    const int j = tid & 31;
    double cb[32];
#pragma unroll
    for (int m = 0; m < 32; ++m) cb[m] = sm.W4[0][m * LDA + j];
#pragma unroll
    for (int t = 0; t < 4; ++t) {
      const int i = 8 * t + (tid >> 5);
      double acc = 0.0;
#pragma unroll
      for (int m = 0; m < 32; ++m)
        acc = fma(sm.W4[1][i * LDA + m], cb[m], acc);
      outg[(size_t)bc * 1024 + i * 32 + j] = (float)acc;  // coalesced
    }
  }
}

// ================== FALLBACK (Round-3 validated, no ws) ==================

struct SMF {
  double sS[4][32 * LDA];
  double sA[32 * LDA];
  double sV[32 * LDA];
  double sSq[32 * LDA];
  double sSi[32 * LDA];
  double sT1[32 * LDA];
  double red[NTH];
  double cs16[16], sn16[16];
  double ew[32];
  double wk[4];
  int pr[16], qr[16];
};

__device__ inline void f_mm_nn(double* __restrict__ D, const double* __restrict__ A,
                               const double* __restrict__ B, int tid) {
  for (int idx = tid; idx < 1024; idx += NTH) {
    int i = idx >> 5, j = idx & 31;
    double acc = 0.0;
#pragma unroll
    for (int m = 0; m < 32; ++m) acc = fma(A[i * LDA + m], B[m * LDA + j], acc);
    D[i * LDA + j] = acc;
  }
}

__device__ inline void f_mm_nt(double* __restrict__ D, const double* __restrict__ A,
                               const double* __restrict__ B, int tid) {
  for (int idx = tid; idx < 1024; idx += NTH) {
    int i = idx >> 5, j = idx & 31;
    double acc = 0.0;
#pragma unroll
    for (int m = 0; m < 32; ++m) acc = fma(A[i * LDA + m], B[j * LDA + m], acc);
    D[i * LDA + j] = acc;
  }
}

template <bool ACC>
__device__ inline void f_mm_nt_ws(double* __restrict__ D, const double* __restrict__ A,
                                  const double* __restrict__ B, double w, int tid) {
  for (int idx = tid; idx < 1024; idx += NTH) {
    int i = idx >> 5, j = idx & 31;
    double acc = 0.0;
#pragma unroll
    for (int m = 0; m < 32; ++m) acc = fma(A[i * LDA + m], B[j * LDA + m], acc);
    if (ACC) D[i * LDA + j] = fma(w, acc, D[i * LDA + j]);
    else     D[i * LDA + j] = w * acc;
  }
}

__device__ void f_jacobi_eigh(double* __restrict__ A, double* __restrict__ V,
                              SMF& sm, int tid) {
  for (int idx = tid; idx < 1024; idx += NTH) {
    int i = idx >> 5, j = idx & 31;
    V[i * LDA + j] = (i == j) ? 1.0 : 0.0;
  }
  double loc = 0.0;
  for (int idx = tid; idx < 1024; idx += NTH) {
    int i = idx >> 5, j = idx & 31;
    double v = A[i * LDA + j];
    loc += v * v;
  }
  sm.red[tid] = loc;
  __syncthreads();
  for (int s = NTH / 2; s > 0; s >>= 1) {
    if (tid < s) sm.red[tid] += sm.red[tid + s];
    __syncthreads();
  }
  double tol2 = 1e-28 * sm.red[0];

  for (int sweep = 0; sweep < 15; ++sweep) {
    double lo = 0.0;
    for (int idx = tid; idx < 1024; idx += NTH) {
      int i = idx >> 5, j = idx & 31;
      if (i != j) {
        double v = A[i * LDA + j];
        lo += v * v;
      }
    }
    __syncthreads();
    sm.red[tid] = lo;
    __syncthreads();
    for (int s = NTH / 2; s > 0; s >>= 1) {
      if (tid < s) sm.red[tid] += sm.red[tid + s];
      __syncthreads();
    }
    if (sm.red[0] <= tol2) break;

    for (int r = 0; r < 31; ++r) {
      if (tid < 16) {
        int p, q;
        if (tid == 0) { p = 31; q = r % 31; }
        else {
          p = (r + tid) % 31;
          q = (r - tid + 31) % 31;
        }
        if (p > q) { int t = p; p = q; q = t; }
        double app = A[p * LDA + p], aqq = A[q * LDA + q], apq = A[p * LDA + q];
        double c = 1.0, s = 0.0;
        if (fabs(apq) > 1e-300) {
          double tau = (aqq - app) / (2.0 * apq);
          double t = ((tau >= 0.0) ? 1.0 : -1.0) / (fabs(tau) + sqrt(1.0 + tau * tau));
          c = 1.0 / sqrt(1.0 + t * t);
          s = t * c;
        }
        sm.pr[tid] = p; sm.qr[tid] = q; sm.cs16[tid] = c; sm.sn16[tid] = s;
      }
      __syncthreads();
      for (int idx = tid; idx < 512; idx += NTH) {
        int pi = idx >> 5, j = idx & 31;
        int p = sm.pr[pi], q = sm.qr[pi];
        double c = sm.cs16[pi], s = sm.sn16[pi];
        double ap = A[p * LDA + j], aq = A[q * LDA + j];
        A[p * LDA + j] = c * ap - s * aq;
        A[q * LDA + j] = s * ap + c * aq;
      }
      __syncthreads();
      for (int idx = tid; idx < 512; idx += NTH) {
        int pi = idx >> 5, j = idx & 31;
        int p = sm.pr[pi], q = sm.qr[pi];
        double c = sm.cs16[pi], s = sm.sn16[pi];
        double ap = A[j * LDA + p], aq = A[j * LDA + q];
        A[j * LDA + p] = c * ap - s * aq;
        A[j * LDA + q] = s * ap + c * aq;
        ap = V[j * LDA + p]; aq = V[j * LDA + q];
        V[j * LDA + p] = c * ap - s * aq;
        V[j * LDA + q] = s * ap + c * aq;
      }
      __syncthreads();
    }
  }
  if (tid < 32) sm.ew[tid] = A[tid * LDA + tid];
  __syncthreads();
}

__global__ __launch_bounds__(NTH) void mixedop_kernel_fb(
    const float* __restrict__ xg, const float* __restrict__ wg,
    const float* __restrict__ Wg, float* __restrict__ outg) {
  __shared__ SMF sm;
  const int bc = blockIdx.x;
  const int tid = threadIdx.x;

  if (tid < 4) sm.wk[tid] = (double)wg[tid];

  float* Xs = (float*)sm.sA;
  double* Ys = (double*)((char*)sm.sA + 16640);
  float* Wks = (float*)sm.sT1;

  const float* xsrc = xg + (size_t)bc * 4096;
  for (int idx = tid; idx < 4096; idx += NTH) {
    int i = idx >> 6, j = idx & 63;
    Xs[i * 65 + j] = xsrc[idx];
  }
  __syncthreads();

  for (int k = 0; k < 4; ++k) {
    const float* wsrc = Wg + k * 2048;
    for (int idx = tid; idx < 2048; idx += NTH) {
      int o = idx >> 6, i = idx & 63;
      Wks[o * 65 + i] = wsrc[idx];
    }
    __syncthreads();
    for (int idx = tid; idx < 2048; idx += NTH) {
      int o = idx >> 6, j = idx & 63;
      double acc = 0.0;
#pragma unroll 8
      for (int i = 0; i < 64; ++i)
        acc = fma((double)Wks[o * 65 + i], (double)Xs[i * 65 + j], acc);
      Ys[o * 65 + j] = acc;
    }
    __syncthreads();
    double* Sk = sm.sS[k];
    for (int idx = tid; idx < 1024; idx += NTH) {
      int o = idx >> 5, p = idx & 31;
      double acc = 0.0;
#pragma unroll 8
      for (int j = 0; j < 64; ++j)
        acc = fma(Ys[o * 65 + j], (double)Wks[p * 65 + j], acc);
      Sk[o * LDA + p] = acc;
    }
    __syncthreads();
  }

  for (int idx = tid; idx < 1024; idx += NTH) {
    int i = idx >> 5, j = idx & 31;
    double g = 0.0;
#pragma unroll
    for (int k = 0; k < 4; ++k) g = fma(sm.wk[k], sm.sS[k][i * LDA + j], g);
    sm.sA[i * LDA + j] = g;
  }
  __syncthreads();

  f_jacobi_eigh(sm.sA, sm.sV, sm, tid);
  for (int idx = tid; idx < 1024; idx += NTH) {
    int i = idx >> 5, m = idx & 31;
    sm.sT1[i * LDA + m] = sm.sV[i * LDA + m] * sqrt(fmax(sm.ew[m], 0.0));
  }
  __syncthreads();
  f_mm_nt(sm.sSq, sm.sT1, sm.sV, tid);
  __syncthreads();
  for (int idx = tid; idx < 1024; idx += NTH) {
    int i = idx >> 5, m = idx & 31;
    sm.sT1[i * LDA + m] = sm.sV[i * LDA + m] / sqrt(fmax(sm.ew[m], 1e-12));
  }
  __syncthreads();
  f_mm_nt(sm.sSi, sm.sT1, sm.sV, tid);
  __syncthreads();

  double* U = sm.sS[0];
  for (int k = 0; k < 4; ++k) {
    f_mm_nn(sm.sT1, sm.sSi, sm.sS[k], tid);
    __syncthreads();
    f_mm_nn(sm.sA, sm.sT1, sm.sSi, tid);
    __syncthreads();
    f_jacobi_eigh(sm.sA, sm.sV, sm, tid);
    for (int idx = tid; idx < 1024; idx += NTH) {
      int i = idx >> 5, m = idx & 31;
      sm.sT1[i * LDA + m] = sm.sV[i * LDA + m] * log(fmax(sm.ew[m], 1e-12));
    }
    __syncthreads();
    if (k == 0) f_mm_nt_ws<false>(U, sm.sT1, sm.sV, sm.wk[0], tid);
    else        f_mm_nt_ws<true >(U, sm.sT1, sm.sV, sm.wk[k], tid);
    __syncthreads();
  }

  f_jacobi_eigh(U, sm.sV, sm, tid);
  for (int idx = tid; idx < 1024; idx += NTH) {
    int i = idx >> 5, m = idx & 31;
    sm.sT1[i * LDA + m] = sm.sV[i * LDA + m] * exp(sm.ew[m]);
  }
  __syncthreads();
  f_mm_nt(sm.sSi, sm.sT1, sm.sV, tid);
  __syncthreads();

  f_mm_nn(sm.sA, sm.sSq, sm.sSi, tid);
  __syncthreads();
  float* outp = outg + (size_t)bc * 1024;
  for (int idx = tid; idx < 1024; idx += NTH) {
    int i = idx >> 5, j = idx & 31;
    double acc = 0.0;
#pragma unroll
    for (int m = 0; m < 32; ++m)
      acc = fma(sm.sA[i * LDA + m], sm.sSq[m * LDA + j], acc);
    outp[i * 32 + j] = (float)acc;
  }
}

// =========================== launch dispatcher ===========================

extern "C" void kernel_launch(void* const* d_in, const int* in_sizes, int n_in,
                              void* d_out, int out_size, void* d_ws, size_t ws_size,
                              hipStream_t stream) {
  const float* x = (const float*)d_in[0];   // [B,C,64,64] f32
  const float* w = (const float*)d_in[1];   // [4] f32
  const float* Ws = (const float*)d_in[2];  // [4,32,64] f32
  float* out = (float*)d_out;               // [B,C,32,32] f32

  const int nbc = in_sizes[0] / 4096;  // B*C = 2048
  // primary ws layout: s_k f32 [nbc][4][1024] then Sq f64 [nbc][1024]
  const size_t ws_need = (size_t)nbc * 4096 * sizeof(float) +
                         (size_t)nbc * 1024 * sizeof(double);  // 50.33 MB

  if (ws_size >= ws_need) {
    float* ws_s = (float*)d_ws;
    double* ws_sq = (double*)((char*)d_ws + (size_t)nbc * 4096 * sizeof(float));
    mixedop_kernel<<<dim3(nbc), dim3(NTH), 0, stream>>>(x, w, Ws, out, ws_s, ws_sq);
  } else {
    // diagnostic fallback: Round-3 validated kernel (no workspace, ~6.6 ms)
    mixedop_kernel_fb<<<dim3(nbc), dim3(NTH), 0, stream>>>(x, w, Ws, out);
  }
}

// Round 9
// 3468.349 us; speedup vs baseline: 2.1926x; 2.1926x over previous
//
#include <hip/hip_runtime.h>
#include <math.h>

// MixedOp (SPDNet DARTS): per (b,c): s_k = W_k X W_k^T, G0 = sum w_k s_k,
// Sq/Si = G0^{+-1/2} (eigh), T_k = Si s_k Si, L_k = logm(T_k) (eigh),
// U = sum w_k L_k, out = Sq expm(U) Sq (eigh).
//
// Round 7 -> 8 change (single delta): the 32x32 eigh is now a REGISTER-
// RESIDENT one-sided (Hestenes) Jacobi. Round-7's two-sided LDS Jacobi hit
// 1.84e9 bank-conflict cycles (~40% of runtime): rows p, p+16 always share
// a bank for any LDA (16*LDA*2 % 32 == 0) -> structural, unfixable by pad.
// One-sided: lane (j,h) holds half-column j of B=A*W and W in 16+16 f64
// regs; XOR round-robin (m=1..31 pairs {j, j^m}) makes partner exchange a
// __shfl_xor (conflict-free ds_swizzle); Gram + rotation = pure fma.
// Zero LDS ops in the eigh inner loop. lambda_j = b_j . w_j (sign-correct
// for indefinite U), V = W.

#define NTH 256
#define LDA 33  // padded row stride (doubles) for 32x32 LDS matrices

// Wave-internal ordering fence (compiler fence + DS drain); used only at
// LDS producer->consumer handoffs outside eigh. NOT a block barrier.
#define WV_SYNC()                                         \
  do {                                                    \
    asm volatile("s_waitcnt lgkmcnt(0)" ::: "memory");    \
    __builtin_amdgcn_sched_barrier(0);                    \
  } while (0)

struct SM {
  double W4[4][32 * LDA];  // work mats: phase1 staging overlay / T_k / L'_k
  double V4[4][32 * LDA];  // eigenvector mats / temps
  double Si[32 * LDA];     // G0^{-1/2}
  double ew4[4][32];       // eigenvalues per wave-slot
};
// Phase-1 staging overlay on W4/V4 (byte offsets from &W4[0][0]):
//   Xs  f32 [64][65]  @ 0      (16640 B)
//   Ys  f64 [32][65]  @ 16640  (16640 B)
//   Wst f32 [32][65]  @ 33280  ( 8320 B)
//   G0  f64 [1056]    @ 41600  ( 8448 B)   (all < 67584 = W4+V4)

// ---- wave-local matmul D = A*B (32x32, LDS, stride LDA), 64 lanes ----
__device__ inline void mm_nn_wave(double* __restrict__ D, const double* __restrict__ A,
                                  const double* __restrict__ B, int lane) {
  const int j = lane & 31, hi = lane >> 5;
  double cb[32];
#pragma unroll
  for (int m = 0; m < 32; ++m) cb[m] = B[m * LDA + j];
#pragma unroll 4
  for (int t = 0; t < 16; ++t) {
    const int i = 2 * t + hi;
    double acc = 0.0;
#pragma unroll
    for (int m = 0; m < 32; ++m) acc = fma(A[i * LDA + m], cb[m], acc);
    D[i * LDA + j] = acc;
  }
}

// ---- block-wide matmul D = A*B (32x32), 256 threads ----
__device__ inline void mm_nn_blk(double* __restrict__ D, const double* __restrict__ A,
                                 const double* __restrict__ B, int tid) {
  const int j = tid & 31;
  double cb[32];
#pragma unroll
  for (int m = 0; m < 32; ++m) cb[m] = B[m * LDA + j];
#pragma unroll
  for (int t = 0; t < 4; ++t) {
    const int i = 8 * t + (tid >> 5);
    double acc = 0.0;
#pragma unroll
    for (int m = 0; m < 32; ++m) acc = fma(A[i * LDA + m], cb[m], acc);
    D[i * LDA + j] = acc;
  }
}

// ---- one-sided (Hestenes) Jacobi eigh of symmetric 32x32 A ----
// Reads A from LDS (not destroyed); writes eigenvector columns to V (LDS)
// and eigenvalues to ewv. Runs on ONE 64-lane wave, fully register-resident:
// lane (j = lane&31, h = lane>>5) holds rows [16h..16h+15] of column j of
// B (= A*W, invariant) and of W (starts I). Round m pairs columns {j, j^m};
// both pair lanes compute identical (c,s) -> no divergence hazard. At
// convergence W = V (up to sign) and lambda_j = b_j . w_j (sign-correct).
__device__ void eigh_onesided(const double* __restrict__ A, double* __restrict__ V,
                              double* __restrict__ ewv, int lane) {
  const int j = lane & 31, h = lane >> 5;
  double b[16], w[16];
#pragma unroll
  for (int i = 0; i < 16; ++i) {
    b[i] = A[(h * 16 + i) * LDA + j];  // column j, half h
    w[i] = (h * 16 + i == j) ? 1.0 : 0.0;
  }
  for (int sweep = 0; sweep < 12; ++sweep) {
    bool any_rot = false;
    for (int m = 1; m < 32; ++m) {
      const int pj = j ^ m;  // partner column
      // own column norm^2 (both halves)
      double on2 = 0.0;
#pragma unroll
      for (int i = 0; i < 16; ++i) on2 = fma(b[i], b[i], on2);
      on2 += __shfl_xor(on2, 32, 64);
      // partner half-column of B
      double tp[16];
#pragma unroll
      for (int i = 0; i < 16; ++i) tp[i] = __shfl_xor(b[i], m, 64);
      // cross dot (both halves)
      double cr = 0.0;
#pragma unroll
      for (int i = 0; i < 16; ++i) cr = fma(b[i], tp[i], cr);
      cr += __shfl_xor(cr, 32, 64);
      const double op2 = __shfl_xor(on2, m, 64);
      // rotate iff |g_pq| > 1e-9 * sqrt(g_pp g_qq); pair-uniform decision
      if (cr * cr > 1e-18 * on2 * op2) {
        any_rot = true;
        const double gpp = (j < pj) ? on2 : op2;
        const double gqq = (j < pj) ? op2 : on2;
        const double tau = (gqq - gpp) / (2.0 * cr);
        const double t = ((tau >= 0.0) ? 1.0 : -1.0) /
                         (fabs(tau) + sqrt(1.0 + tau * tau));
        const double c = 1.0 / sqrt(1.0 + t * t);
        const double s = t * c;
        const double ss = (j < pj) ? -s : s;  // col_p: c*p - s*q ; col_q: s*p + c*q
#pragma unroll
        for (int i = 0; i < 16; ++i) b[i] = fma(ss, tp[i], c * b[i]);
        // partner half-column of W (w not yet updated on either side)
#pragma unroll
        for (int i = 0; i < 16; ++i) tp[i] = __shfl_xor(w[i], m, 64);
#pragma unroll
        for (int i = 0; i < 16; ++i) w[i] = fma(ss, tp[i], c * w[i]);
      }
    }
    if (!__any(any_rot)) break;  // converged: a full sweep with no rotation
  }
  // lambda_j = b_j . w_j ; V column j = w
  double lam = 0.0;
#pragma unroll
  for (int i = 0; i < 16; ++i) lam = fma(b[i], w[i], lam);
  lam += __shfl_xor(lam, 32, 64);
#pragma unroll
  for (int i = 0; i < 16; ++i) V[(h * 16 + i) * LDA + j] = w[i];
  if (h == 0) ewv[j] = lam;
  WV_SYNC();  // V/ewv visible to same-wave consumers in program order
}

__global__ __launch_bounds__(NTH, 2) void mixedop_kernel(
    const float* __restrict__ xg, const float* __restrict__ wg,
    const float* __restrict__ Wg, float* __restrict__ outg,
    float* __restrict__ ws_s, double* __restrict__ ws_sq) {
  __shared__ SM sm;
  const int bc = blockIdx.x;
  const int tid = threadIdx.x;
  const int lane = tid & 63;
  const int wv = tid >> 6;

  // staging overlay pointers
  char* base = (char*)&sm.W4[0][0];
  float* Xs = (float*)base;                    // [64][65]
  double* Ys = (double*)(base + 16640);        // [32][65]
  float* Wst = (float*)(base + 33280);         // [32][65]
  double* G0 = (double*)(base + 41600);        // [1056]

  // ---- Phase 1: X load, G0 zero ----
  for (int idx = tid; idx < 1056; idx += NTH) G0[idx] = 0.0;
  const float* xsrc = xg + (size_t)bc * 4096;
  for (int idx = tid; idx < 4096; idx += NTH)
    Xs[(idx >> 6) * 65 + (idx & 63)] = xsrc[idx];
  __syncthreads();

  for (int k = 0; k < 4; ++k) {
    const float* wsrc = Wg + k * 2048;
    for (int idx = tid; idx < 2048; idx += NTH)
      Wst[(idx >> 6) * 65 + (idx & 63)] = wsrc[idx];
    __syncthreads();
    // Y = W_k * X  [32 x 64], X-column cached in regs
    {
      const int j = tid & 63;
      float cx[64];
#pragma unroll
      for (int m = 0; m < 64; ++m) cx[m] = Xs[m * 65 + j];
#pragma unroll
      for (int t = 0; t < 8; ++t) {
        const int o = 4 * t + (tid >> 6);
        double acc = 0.0;
#pragma unroll
        for (int m = 0; m < 64; ++m)
          acc = fma((double)Wst[o * 65 + m], (double)cx[m], acc);
        Ys[o * 65 + j] = acc;
      }
    }
    __syncthreads();
    // s_k = Y * W_k^T -> ws (f32) ; G0 += w_k s_k  (f64)
    {
      const double wkk = (double)wg[k];
      const int p = tid & 31;
      float cw[64];
#pragma unroll
      for (int m = 0; m < 64; ++m) cw[m] = Wst[p * 65 + m];
#pragma unroll
      for (int t = 0; t < 4; ++t) {
        const int o = 8 * t + (tid >> 5);
        double acc = 0.0;
#pragma unroll
        for (int m = 0; m < 64; ++m)
          acc = fma(Ys[o * 65 + m], (double)cw[m], acc);
        const int e = o * 32 + p;  // == 256*t + tid (coalesced)
        ws_s[(size_t)bc * 4096 + k * 1024 + e] = (float)acc;
        G0[o * LDA + p] += wkk * acc;
      }
    }
    __syncthreads();
  }

  // ---- Phase 3: eigh(G0) -> Sq (to ws), Si (LDS) ----
  for (int idx = tid; idx < 1024; idx += NTH) {
    const int i = idx >> 5, j = idx & 31;
    sm.W4[0][i * LDA + j] = G0[i * LDA + j];
  }
  __syncthreads();
  if (wv == 0) eigh_onesided(sm.W4[0], sm.V4[0], sm.ew4[0], lane);
  __syncthreads();
  {  // P = V D^{1/2} -> W4[1] ; P2 = V D^{-1/2} -> W4[2]
    const int j = tid & 31;
    const double lam = sm.ew4[0][j];
    const double sq = sqrt(fmax(lam, 0.0));
    const double isq = 1.0 / sqrt(fmax(lam, 1e-12));
#pragma unroll
    for (int t = 0; t < 4; ++t) {
      const int i = 8 * t + (tid >> 5);
      const double v = sm.V4[0][i * LDA + j];
      sm.W4[1][i * LDA + j] = v * sq;
      sm.W4[2][i * LDA + j] = v * isq;
    }
  }
  __syncthreads();
  {  // Sq = P V^T -> ws_sq ; Si = P2 V^T -> sm.Si   (B^T: cache V row j)
    const int j = tid & 31;
    double cb[32];
#pragma unroll
    for (int m = 0; m < 32; ++m) cb[m] = sm.V4[0][j * LDA + m];
#pragma unroll
    for (int t = 0; t < 4; ++t) {
      const int i = 8 * t + (tid >> 5);
      double a1 = 0.0, a2 = 0.0;
#pragma unroll
      for (int m = 0; m < 32; ++m) {
        a1 = fma(sm.W4[1][i * LDA + m], cb[m], a1);
        a2 = fma(sm.W4[2][i * LDA + m], cb[m], a2);
      }
      ws_sq[(size_t)bc * 1024 + i * 32 + j] = a1;  // coalesced
      sm.Si[i * LDA + j] = a2;
    }
  }
  __syncthreads();

  // ---- Phase 4/5: per wave k: T_k = Si s_k Si ; eigh ; L'_k = w_k V log V^T ----
  {
    const int k = wv;
    double* Ak = sm.W4[k];
    double* Vk = sm.V4[k];
    // stage s_k from ws (f32 -> f64)
    for (int t = 0; t < 16; ++t) {
      const int e = t * 64 + lane;
      Ak[(e >> 5) * LDA + (e & 31)] =
          (double)ws_s[(size_t)bc * 4096 + k * 1024 + e];
    }
    WV_SYNC();
    mm_nn_wave(Vk, sm.Si, Ak, lane);  // R = Si * s_k
    WV_SYNC();
    mm_nn_wave(Ak, Vk, sm.Si, lane);  // T = R * Si
    WV_SYNC();
    eigh_onesided(Ak, Vk, sm.ew4[k], lane);
    {  // P = V diag(log lam) -> Ak (input no longer needed)
      const int j = lane & 31, hi = lane >> 5;
      const double lgl = log(fmax(sm.ew4[k][j], 1e-12));
#pragma unroll
      for (int t = 0; t < 16; ++t) {
        const int i = 2 * t + hi;
        Ak[i * LDA + j] = Vk[i * LDA + j] * lgl;
      }
    }
    WV_SYNC();
    {  // L'_k = w_k * P * V^T -> regs -> overwrite Ak (reads all precede writes)
      const double wkk = (double)wg[k];
      const int j = lane & 31, hi = lane >> 5;
      double cb[32];
#pragma unroll
      for (int m = 0; m < 32; ++m) cb[m] = Vk[j * LDA + m];
      double accv[16];
#pragma unroll
      for (int t = 0; t < 16; ++t) {
        const int i = 2 * t + hi;
        double a = 0.0;
#pragma unroll
        for (int m = 0; m < 32; ++m) a = fma(Ak[i * LDA + m], cb[m], a);
        accv[t] = wkk * a;
      }
      WV_SYNC();
#pragma unroll
      for (int t = 0; t < 16; ++t) Ak[(2 * t + hi) * LDA + j] = accv[t];
    }
  }
  __syncthreads();

  // ---- Phase 6: U = sum L'_k ; eigh(U) ; E = expm(U) ----
  for (int idx = tid; idx < 1024; idx += NTH) {
    const int i = idx >> 5, j = idx & 31;
    sm.V4[1][i * LDA + j] = sm.W4[0][i * LDA + j] + sm.W4[1][i * LDA + j] +
                            sm.W4[2][i * LDA + j] + sm.W4[3][i * LDA + j];
  }
  __syncthreads();
  if (wv == 0) eigh_onesided(sm.V4[1], sm.V4[0], sm.ew4[0], lane);
  __syncthreads();
  {  // Pe = V diag(exp) -> V4[2]
    const int j = tid & 31;
    const double ex = exp(sm.ew4[0][j]);
#pragma unroll
    for (int t = 0; t < 4; ++t) {
      const int i = 8 * t + (tid >> 5);
      sm.V4[2][i * LDA + j] = sm.V4[0][i * LDA + j] * ex;
    }
  }
  __syncthreads();
  {  // E = Pe V^T -> V4[3]
    const int j = tid & 31;
    double cb[32];
#pragma unroll
    for (int m = 0; m < 32; ++m) cb[m] = sm.V4[0][j * LDA + m];
#pragma unroll
    for (int t = 0; t < 4; ++t) {
      const int i = 8 * t + (tid >> 5);
      double acc = 0.0;
#pragma unroll
      for (int m = 0; m < 32; ++m) acc = fma(sm.V4[2][i * LDA + m], cb[m], acc);
      sm.V4[3][i * LDA + j] = acc;
    }
  }
  __syncthreads();
  // reload Sq
  for (int idx = tid; idx < 1024; idx += NTH)
    sm.W4[0][(idx >> 5) * LDA + (idx & 31)] = ws_sq[(size_t)bc * 1024 + idx];
  __syncthreads();
  mm_nn_blk(sm.W4[1], sm.W4[0], sm.V4[3], tid);  // F1 = Sq * E
  __syncthreads();
  {  // out = F1 * Sq -> global f32
    const int j = tid & 31;
    double cb[32];
#pragma unroll
    for (int m = 0; m < 32; ++m) cb[m] = sm.W4[0][m * LDA + j];
#pragma unroll
    for (int t = 0; t < 4; ++t) {
      const int i = 8 * t + (tid >> 5);
      double acc = 0.0;
#pragma unroll
      for (int m = 0; m < 32; ++m)
        acc = fma(sm.W4[1][i * LDA + m], cb[m], acc);
      outg[(size_t)bc * 1024 + i * 32 + j] = (float)acc;  // coalesced
    }
  }
}

extern "C" void kernel_launch(void* const* d_in, const int* in_sizes, int n_in,
                              void* d_out, int out_size, void* d_ws, size_t ws_size,
                              hipStream_t stream) {
  const float* x = (const float*)d_in[0];   // [B,C,64,64] f32
  const float* w = (const float*)d_in[1];   // [4] f32
  const float* Ws = (const float*)d_in[2];  // [4,32,64] f32
  float* out = (float*)d_out;               // [B,C,32,32] f32

  const int nbc = in_sizes[0] / 4096;  // B*C = 2048
  // ws layout: s_k f32 [nbc][4][1024] then Sq f64 [nbc][1024]  (~50.3 MB;
  // proven sufficient in Round 7 — primary path ran)
  float* ws_s = (float*)d_ws;
  double* ws_sq = (double*)((char*)d_ws + (size_t)nbc * 4096 * sizeof(float));

  mixedop_kernel<<<dim3(nbc), dim3(NTH), 0, stream>>>(x, w, Ws, out, ws_s, ws_sq);
}

// Round 14
// 3282.168 us; speedup vs baseline: 2.3170x; 1.0567x over previous
//
#include <hip/hip_runtime.h>
#include <math.h>

// MixedOp (SPDNet DARTS): per (b,c): s_k = W_k X W_k^T, G0 = sum w_k s_k,
// Sq/Si = G0^{+-1/2} (eigh), T_k = Si s_k Si, L_k = logm(T_k) (eigh),
// U = sum w_k L_k, out = Sq expm(U) Sq (eigh).
//
// Pending delta (vs Round-9-measured 3468 us), all inside eigh_onesided:
//  (a) tracked column norms: g_pp kept in a register, updated analytically
//      (gpp' = gpp - t*g_pq, gqq' = gqq + t*g_pq), refreshed each sweep ->
//      removes a 16-deep f64 fma chain + 1 f64 shuffle per round;
//  (b) 4-way split accumulators for the cross-dot (chain ~128cy -> ~40cy);
//  (c) fast f64 rcp/rsqrt (f32 HW approx + 2 Newton steps, ~1e-24 rel) for
//      tau / sqrt(1+tau^2) / 1/sqrt(1+t^2) -> replaces ~3 f64 div/sqrt
//      library sequences (~200-300cy) on the rotation critical path.
// Pair lanes run bitwise-identical sequences on identical inputs -> (c,s)
// stay pair-uniform; B = A*W remains exact for any (c,s) applied to both.

#define NTH 256
#define LDA 33  // padded row stride (doubles) for 32x32 LDS matrices

// Wave-internal ordering fence (compiler fence + DS drain); used only at
// LDS producer->consumer handoffs outside eigh. NOT a block barrier.
#define WV_SYNC()                                         \
  do {                                                    \
    asm volatile("s_waitcnt lgkmcnt(0)" ::: "memory");    \
    __builtin_amdgcn_sched_barrier(0);                    \
  } while (0)

struct SM {
  double W4[4][32 * LDA];  // work mats: phase1 staging overlay / T_k / L'_k
  double V4[4][32 * LDA];  // eigenvector mats / temps
  double Si[32 * LDA];     // G0^{-1/2}
  double ew4[4][32];       // eigenvalues per wave-slot
};
// Phase-1 staging overlay on W4/V4 (byte offsets from &W4[0][0]):
//   Xs  f32 [64][65]  @ 0      (16640 B)
//   Ys  f64 [32][65]  @ 16640  (16640 B)
//   Wst f32 [32][65]  @ 33280  ( 8320 B)
//   G0  f64 [1056]    @ 41600  ( 8448 B)   (all < 67584 = W4+V4)

// f64 reciprocal via f32 HW approx + 2 Newton steps (~1e-24 rel; exact-ish).
__device__ inline double fast_rcp(double x) {
  double r = (double)(1.0f / (float)x);
  r = r * (2.0 - x * r);
  r = r * (2.0 - x * r);
  return r;
}
// f64 1/sqrt via f32 HW approx + 2 Newton steps.
__device__ inline double fast_rsqrt(double x) {
  double r = (double)rsqrtf((float)x);
  r = r * (1.5 - 0.5 * x * r * r);
  r = r * (1.5 - 0.5 * x * r * r);
  return r;
}

// ---- wave-local matmul D = A*B (32x32, LDS, stride LDA), 64 lanes ----
__device__ inline void mm_nn_wave(double* __restrict__ D, const double* __restrict__ A,
                                  const double* __restrict__ B, int lane) {
  const int j = lane & 31, hi = lane >> 5;
  double cb[32];
#pragma unroll
  for (int m = 0; m < 32; ++m) cb[m] = B[m * LDA + j];
#pragma unroll 4
  for (int t = 0; t < 16; ++t) {
    const int i = 2 * t + hi;
    double acc = 0.0;
#pragma unroll
    for (int m = 0; m < 32; ++m) acc = fma(A[i * LDA + m], cb[m], acc);
    D[i * LDA + j] = acc;
  }
}

// ---- block-wide matmul D = A*B (32x32), 256 threads ----
__device__ inline void mm_nn_blk(double* __restrict__ D, const double* __restrict__ A,
                                 const double* __restrict__ B, int tid) {
  const int j = tid & 31;
  double cb[32];
#pragma unroll
  for (int m = 0; m < 32; ++m) cb[m] = B[m * LDA + j];
#pragma unroll
  for (int t = 0; t < 4; ++t) {
    const int i = 8 * t + (tid >> 5);
    double acc = 0.0;
#pragma unroll
    for (int m = 0; m < 32; ++m) acc = fma(A[i * LDA + m], cb[m], acc);
    D[i * LDA + j] = acc;
  }
}

// ---- one-sided (Hestenes) Jacobi eigh of symmetric 32x32 A ----
// Reads A from LDS (not destroyed); writes eigenvector columns to V (LDS)
// and eigenvalues to ewv. ONE 64-lane wave, register-resident: lane
// (j = lane&31, h = lane>>5) holds rows [16h..16h+15] of column j of
// B (= A*W, invariant) and of W (starts I). Round m pairs columns {j, j^m}.
__device__ void eigh_onesided(const double* __restrict__ A, double* __restrict__ V,
                              double* __restrict__ ewv, int lane) {
  const int j = lane & 31, h = lane >> 5;
  double b[16], w[16];
#pragma unroll
  for (int i = 0; i < 16; ++i) {
    b[i] = A[(h * 16 + i) * LDA + j];  // column j, half h
    w[i] = (h * 16 + i == j) ? 1.0 : 0.0;
  }
  for (int sweep = 0; sweep < 12; ++sweep) {
    // refresh tracked ||col_j||^2 (4-way split chains, then xor-32 combine)
    double n0 = 0.0, n1 = 0.0, n2 = 0.0, n3 = 0.0;
#pragma unroll
    for (int i = 0; i < 16; i += 4) {
      n0 = fma(b[i + 0], b[i + 0], n0);
      n1 = fma(b[i + 1], b[i + 1], n1);
      n2 = fma(b[i + 2], b[i + 2], n2);
      n3 = fma(b[i + 3], b[i + 3], n3);
    }
    double on2 = (n0 + n1) + (n2 + n3);
    on2 += __shfl_xor(on2, 32, 64);

    bool any_rot = false;
    for (int m = 1; m < 32; ++m) {
      const int pj = j ^ m;  // partner column
      // partner half-column of B
      double tp[16];
#pragma unroll
      for (int i = 0; i < 16; ++i) tp[i] = __shfl_xor(b[i], m, 64);
      // cross dot (4-way split; both pair lanes -> bitwise-identical cr)
      double c0 = 0.0, c1 = 0.0, c2 = 0.0, c3 = 0.0;
#pragma unroll
      for (int i = 0; i < 16; i += 4) {
        c0 = fma(b[i + 0], tp[i + 0], c0);
        c1 = fma(b[i + 1], tp[i + 1], c1);
        c2 = fma(b[i + 2], tp[i + 2], c2);
        c3 = fma(b[i + 3], tp[i + 3], c3);
      }
      double cr = (c0 + c1) + (c2 + c3);
      cr += __shfl_xor(cr, 32, 64);
      const double op2 = __shfl_xor(on2, m, 64);
      // rotate iff |g_pq| > 1e-9 * sqrt(g_pp g_qq); pair-uniform decision
      if (cr * cr > 1e-18 * on2 * op2) {
        any_rot = true;
        const double gpp = (j < pj) ? on2 : op2;
        const double gqq = (j < pj) ? op2 : on2;
        const double tau = (gqq - gpp) * fast_rcp(2.0 * cr);
        const double yt = 1.0 + tau * tau;
        const double rs = fast_rsqrt(yt);   // 1/sqrt(1+tau^2)
        const double den = fabs(tau) + yt * rs;  // |tau| + sqrt(1+tau^2)
        const double t = ((tau >= 0.0) ? 1.0 : -1.0) * fast_rcp(den);
        const double c = fast_rsqrt(1.0 + t * t);
        const double s = t * c;
        const double ss = (j < pj) ? -s : s;  // col_p: c*p - s*q ; col_q: s*p + c*q
#pragma unroll
        for (int i = 0; i < 16; ++i) b[i] = fma(ss, tp[i], c * b[i]);
        // partner half-column of W (w not yet updated on either side)
#pragma unroll
        for (int i = 0; i < 16; ++i) tp[i] = __shfl_xor(w[i], m, 64);
#pragma unroll
        for (int i = 0; i < 16; ++i) w[i] = fma(ss, tp[i], c * w[i]);
        // tracked-norm update (Golub & Van Loan): gpp' = gpp - t*g_pq, etc.
        on2 = (j < pj) ? fma(-t, cr, on2) : fma(t, cr, on2);
      }
    }
    if (!__any(any_rot)) break;  // converged: full sweep with no rotation
  }
  // lambda_j = b_j . w_j (4-way split) ; V column j = w
  double l0 = 0.0, l1 = 0.0, l2 = 0.0, l3 = 0.0;
#pragma unroll
  for (int i = 0; i < 16; i += 4) {
    l0 = fma(b[i + 0], w[i + 0], l0);
    l1 = fma(b[i + 1], w[i + 1], l1);
    l2 = fma(b[i + 2], w[i + 2], l2);
    l3 = fma(b[i + 3], w[i + 3], l3);
  }
  double lam = (l0 + l1) + (l2 + l3);
  lam += __shfl_xor(lam, 32, 64);
#pragma unroll
  for (int i = 0; i < 16; ++i) V[(h * 16 + i) * LDA + j] = w[i];
  if (h == 0) ewv[j] = lam;
  WV_SYNC();  // V/ewv visible to same-wave consumers in program order
}

__global__ __launch_bounds__(NTH, 2) void mixedop_kernel(
    const float* __restrict__ xg, const float* __restrict__ wg,
    const float* __restrict__ Wg, float* __restrict__ outg,
    float* __restrict__ ws_s, double* __restrict__ ws_sq) {
  __shared__ SM sm;
  const int bc = blockIdx.x;
  const int tid = threadIdx.x;
  const int lane = tid & 63;
  const int wv = tid >> 6;

  // staging overlay pointers
  char* base = (char*)&sm.W4[0][0];
  float* Xs = (float*)base;                    // [64][65]
  double* Ys = (double*)(base + 16640);        // [32][65]
  float* Wst = (float*)(base + 33280);         // [32][65]
  double* G0 = (double*)(base + 41600);        // [1056]

  // ---- Phase 1: X load, G0 zero ----
  for (int idx = tid; idx < 1056; idx += NTH) G0[idx] = 0.0;
  const float* xsrc = xg + (size_t)bc * 4096;
  for (int idx = tid; idx < 4096; idx += NTH)
    Xs[(idx >> 6) * 65 + (idx & 63)] = xsrc[idx];
  __syncthreads();

  for (int k = 0; k < 4; ++k) {
    const float* wsrc = Wg + k * 2048;
    for (int idx = tid; idx < 2048; idx += NTH)
      Wst[(idx >> 6) * 65 + (idx & 63)] = wsrc[idx];
    __syncthreads();
    // Y = W_k * X  [32 x 64], X-column cached in regs
    {
      const int j = tid & 63;
      float cx[64];
#pragma unroll
      for (int m = 0; m < 64; ++m) cx[m] = Xs[m * 65 + j];
#pragma unroll
      for (int t = 0; t < 8; ++t) {
        const int o = 4 * t + (tid >> 6);
        double acc = 0.0;
#pragma unroll
        for (int m = 0; m < 64; ++m)
          acc = fma((double)Wst[o * 65 + m], (double)cx[m], acc);
        Ys[o * 65 + j] = acc;
      }
    }
    __syncthreads();
    // s_k = Y * W_k^T -> ws (f32) ; G0 += w_k s_k  (f64)
    {
      const double wkk = (double)wg[k];
      const int p = tid & 31;
      float cw[64];
#pragma unroll
      for (int m = 0; m < 64; ++m) cw[m] = Wst[p * 65 + m];
#pragma unroll
      for (int t = 0; t < 4; ++t) {
        const int o = 8 * t + (tid >> 5);
        double acc = 0.0;
#pragma unroll
        for (int m = 0; m < 64; ++m)
          acc = fma(Ys[o * 65 + m], (double)cw[m], acc);
        const int e = o * 32 + p;  // == 256*t + tid (coalesced)
        ws_s[(size_t)bc * 4096 + k * 1024 + e] = (float)acc;
        G0[o * LDA + p] += wkk * acc;
      }
    }
    __syncthreads();
  }

  // ---- Phase 3: eigh(G0) -> Sq (to ws), Si (LDS) ----
  for (int idx = tid; idx < 1024; idx += NTH) {
    const int i = idx >> 5, j = idx & 31;
    sm.W4[0][i * LDA + j] = G0[i * LDA + j];
  }
  __syncthreads();
  if (wv == 0) eigh_onesided(sm.W4[0], sm.V4[0], sm.ew4[0], lane);
  __syncthreads();
  {  // P = V D^{1/2} -> W4[1] ; P2 = V D^{-1/2} -> W4[2]
    const int j = tid & 31;
    const double lam = sm.ew4[0][j];
    const double sq = sqrt(fmax(lam, 0.0));
    const double isq = 1.0 / sqrt(fmax(lam, 1e-12));
#pragma unroll
    for (int t = 0; t < 4; ++t) {
      const int i = 8 * t + (tid >> 5);
      const double v = sm.V4[0][i * LDA + j];
      sm.W4[1][i * LDA + j] = v * sq;
      sm.W4[2][i * LDA + j] = v * isq;
    }
  }
  __syncthreads();
  {  // Sq = P V^T -> ws_sq ; Si = P2 V^T -> sm.Si   (B^T: cache V row j)
    const int j = tid & 31;
    double cb[32];
#pragma unroll
    for (int m = 0; m < 32; ++m) cb[m] = sm.V4[0][j * LDA + m];
#pragma unroll
    for (int t = 0; t < 4; ++t) {
      const int i = 8 * t + (tid >> 5);
      double a1 = 0.0, a2 = 0.0;
#pragma unroll
      for (int m = 0; m < 32; ++m) {
        a1 = fma(sm.W4[1][i * LDA + m], cb[m], a1);
        a2 = fma(sm.W4[2][i * LDA + m], cb[m], a2);
      }
      ws_sq[(size_t)bc * 1024 + i * 32 + j] = a1;  // coalesced
      sm.Si[i * LDA + j] = a2;
    }
  }
  __syncthreads();

  // ---- Phase 4/5: per wave k: T_k = Si s_k Si ; eigh ; L'_k = w_k V log V^T ----
  {
    const int k = wv;
    double* Ak = sm.W4[k];
    double* Vk = sm.V4[k];
    // stage s_k from ws (f32 -> f64)
    for (int t = 0; t < 16; ++t) {
      const int e = t * 64 + lane;
      Ak[(e >> 5) * LDA + (e & 31)] =
          (double)ws_s[(size_t)bc * 4096 + k * 1024 + e];
    }
    WV_SYNC();
    mm_nn_wave(Vk, sm.Si, Ak, lane);  // R = Si * s_k
    WV_SYNC();
    mm_nn_wave(Ak, Vk, sm.Si, lane);  // T = R * Si
    WV_SYNC();
    eigh_onesided(Ak, Vk, sm.ew4[k], lane);
    {  // P = V diag(log lam) -> Ak (input no longer needed)
      const int j = lane & 31, hi = lane >> 5;
      const double lgl = log(fmax(sm.ew4[k][j], 1e-12));
#pragma unroll
      for (int t = 0; t < 16; ++t) {
        const int i = 2 * t + hi;
        Ak[i * LDA + j] = Vk[i * LDA + j] * lgl;
      }
    }
    WV_SYNC();
    {  // L'_k = w_k * P * V^T -> regs -> overwrite Ak (reads all precede writes)
      const double wkk = (double)wg[k];
      const int j = lane & 31, hi = lane >> 5;
      double cb[32];
#pragma unroll
      for (int m = 0; m < 32; ++m) cb[m] = Vk[j * LDA + m];
      double accv[16];
#pragma unroll
      for (int t = 0; t < 16; ++t) {
        const int i = 2 * t + hi;
        double a = 0.0;
#pragma unroll
        for (int m = 0; m < 32; ++m) a = fma(Ak[i * LDA + m], cb[m], a);
        accv[t] = wkk * a;
      }
      WV_SYNC();
#pragma unroll
      for (int t = 0; t < 16; ++t) Ak[(2 * t + hi) * LDA + j] = accv[t];
    }
  }
  __syncthreads();

  // ---- Phase 6: U = sum L'_k ; eigh(U) ; E = expm(U) ----
  for (int idx = tid; idx < 1024; idx += NTH) {
    const int i = idx >> 5, j = idx & 31;
    sm.V4[1][i * LDA + j] = sm.W4[0][i * LDA + j] + sm.W4[1][i * LDA + j] +
                            sm.W4[2][i * LDA + j] + sm.W4[3][i * LDA + j];
  }
  __syncthreads();
  if (wv == 0) eigh_onesided(sm.V4[1], sm.V4[0], sm.ew4[0], lane);
  __syncthreads();
  {  // Pe = V diag(exp) -> V4[2]
    const int j = tid & 31;
    const double ex = exp(sm.ew4[0][j]);
#pragma unroll
    for (int t = 0; t < 4; ++t) {
      const int i = 8 * t + (tid >> 5);
      sm.V4[2][i * LDA + j] = sm.V4[0][i * LDA + j] * ex;
    }
  }
  __syncthreads();
  {  // E = Pe V^T -> V4[3]
    const int j = tid & 31;
    double cb[32];
#pragma unroll
    for (int m = 0; m < 32; ++m) cb[m] = sm.V4[0][j * LDA + m];
#pragma unroll
    for (int t = 0; t < 4; ++t) {
      const int i = 8 * t + (tid >> 5);
      double acc = 0.0;
#pragma unroll
      for (int m = 0; m < 32; ++m) acc = fma(sm.V4[2][i * LDA + m], cb[m], acc);
      sm.V4[3][i * LDA + j] = acc;
    }
  }
  __syncthreads();
  // reload Sq
  for (int idx = tid; idx < 1024; idx += NTH)
    sm.W4[0][(idx >> 5) * LDA + (idx & 31)] = ws_sq[(size_t)bc * 1024 + idx];
  __syncthreads();
  mm_nn_blk(sm.W4[1], sm.W4[0], sm.V4[3], tid);  // F1 = Sq * E
  __syncthreads();
  {  // out = F1 * Sq -> global f32
    const int j = tid & 31;
    double cb[32];
#pragma unroll
    for (int m = 0; m < 32; ++m) cb[m] = sm.W4[0][m * LDA + j];
#pragma unroll
    for (int t = 0; t < 4; ++t) {
      const int i = 8 * t + (tid >> 5);
      double acc = 0.0;
#pragma unroll
      for (int m = 0; m < 32; ++m)
        acc = fma(sm.W4[1][i * LDA + m], cb[m], acc);
      outg[(size_t)bc * 1024 + i * 32 + j] = (float)acc;  // coalesced
    }
  }
}

extern "C" void kernel_launch(void* const* d_in, const int* in_sizes, int n_in,
                              void* d_out, int out_size, void* d_ws, size_t ws_size,
                              hipStream_t stream) {
  const float* x = (const float*)d_in[0];   // [B,C,64,64] f32
  const float* w = (const float*)d_in[1];   // [4] f32
  const float* Ws = (const float*)d_in[2];  // [4,32,64] f32
  float* out = (float*)d_out;               // [B,C,32,32] f32

  const int nbc = in_sizes[0] / 4096;  // B*C = 2048
  // ws layout: s_k f32 [nbc][4][1024] then Sq f64 [nbc][1024]  (~50.3 MB;
  // proven sufficient — primary path ran in Rounds 7/9)
  float* ws_s = (float*)d_ws;
  double* ws_sq = (double*)((char*)d_ws + (size_t)nbc * 4096 * sizeof(float));

  mixedop_kernel<<<dim3(nbc), dim3(NTH), 0, stream>>>(x, w, Ws, out, ws_s, ws_sq);
}